// Round 8
// baseline (563.053 us; speedup 1.0000x reference)
//
#include <hip/hip_runtime.h>
#include <hip/hip_bf16.h>
#include <cstdint>
#include <cstddef>
#include <cmath>

#define NH 16
#define HD 64
#define SS 2048
#define DM 1024
#define MTOT 4096   // B*S

typedef __attribute__((ext_vector_type(8))) short short8;
typedef __attribute__((ext_vector_type(4))) short short4v;
typedef __attribute__((ext_vector_type(4))) float float4v;
typedef __attribute__((ext_vector_type(4))) int int4v;
typedef __attribute__((ext_vector_type(4))) unsigned short ushort4v;

#if defined(__has_builtin)
# if __has_builtin(__builtin_amdgcn_mfma_f32_16x16x16bf16_1k)
#  define PV_DIRECT 1
# endif
#endif
#ifndef PV_DIRECT
# define PV_DIRECT 0
#endif

__device__ __forceinline__ unsigned short f2bf(float f){
  unsigned int u = __builtin_bit_cast(unsigned int, f);
  u += 0x7FFFu + ((u >> 16) & 1u);   // RNE; inputs finite
  return (unsigned short)(u >> 16);
}

__device__ __forceinline__ void gload16(const void* g, void* l){
  __builtin_amdgcn_global_load_lds((const __attribute__((address_space(1))) void*)g,
                                   (__attribute__((address_space(3))) void*)l, 16, 0, 0);
}

// ---------- f32 -> bf16 bulk convert, z-batched ----------
__global__ __launch_bounds__(256) void cvt3_kernel(
    const float* __restrict__ s0, const float* __restrict__ s1, const float* __restrict__ s2,
    unsigned short* __restrict__ d0, unsigned short* __restrict__ d1, unsigned short* __restrict__ d2,
    int n){
  const int z = blockIdx.z;
  const float* src = z==0 ? s0 : (z==1 ? s1 : s2);
  unsigned short* dst = z==0 ? d0 : (z==1 ? d1 : d2);
  for (int i = (blockIdx.x*blockDim.x + threadIdx.x)*4; i < n; i += gridDim.x*blockDim.x*4){
    float4v v = *reinterpret_cast<const float4v*>(src + i);
    ushort4v o;
    o.x = f2bf(v.x); o.y = f2bf(v.y); o.z = f2bf(v.z); o.w = f2bf(v.w);
    *reinterpret_cast<ushort4v*>(dst + i) = o;
  }
}

__global__ __launch_bounds__(256) void cvt4_kernel(
    const float* __restrict__ s0, const float* __restrict__ s1,
    const float* __restrict__ s2, const float* __restrict__ s3,
    unsigned short* __restrict__ d0, unsigned short* __restrict__ d1,
    unsigned short* __restrict__ d2, unsigned short* __restrict__ d3,
    int n){
  const int z = blockIdx.z;
  const float* src = z==0 ? s0 : (z==1 ? s1 : (z==2 ? s2 : s3));
  unsigned short* dst = z==0 ? d0 : (z==1 ? d1 : (z==2 ? d2 : d3));
  for (int i = (blockIdx.x*blockDim.x + threadIdx.x)*4; i < n; i += gridDim.x*blockDim.x*4){
    float4v v = *reinterpret_cast<const float4v*>(src + i);
    ushort4v o;
    o.x = f2bf(v.x); o.y = f2bf(v.y); o.z = f2bf(v.z); o.w = f2bf(v.w);
    *reinterpret_cast<ushort4v*>(dst + i) = o;
  }
}

// ---------- batched projection GEMM: z in {q,k,v}; z==2 writes V^T ----------
__global__ __launch_bounds__(256) void gemm_proj(
    const unsigned short* __restrict__ X0, const unsigned short* __restrict__ X1, const unsigned short* __restrict__ X2,
    const unsigned short* __restrict__ W0, const unsigned short* __restrict__ W1, const unsigned short* __restrict__ W2,
    const float* __restrict__ b0, const float* __restrict__ b1, const float* __restrict__ b2,
    unsigned short* __restrict__ O0, unsigned short* __restrict__ O1, unsigned short* __restrict__ O2){
  __shared__ unsigned short Alds[128*32];
  __shared__ unsigned short Blds[128*32];
  const int z = blockIdx.z;
  const unsigned short* A  = z==0 ? X0 : (z==1 ? X1 : X2);
  const unsigned short* Bw = z==0 ? W0 : (z==1 ? W1 : W2);
  const float* bias        = z==0 ? b0 : (z==1 ? b1 : b2);
  unsigned short* outp     = z==0 ? O0 : (z==1 ? O1 : O2);
  const bool vmode = (z == 2);
  const int K = DM;
  const int t = threadIdx.x;
  const int l = t & 63;
  const int w = t >> 6;
  const int m0 = blockIdx.y * 128, n0 = blockIdx.x * 128;
  const int wm = (w & 1)*64, wn = (w >> 1)*64;
  const int srow = t >> 2;
  const int scol = (t & 3)*8;
  const int lr = l & 15, lg = l >> 4;
  float4v acc[4][4] = {};
  for (int k0 = 0; k0 < K; k0 += 32){
    __syncthreads();
    gload16(A  + (size_t)(m0 + srow     )*K + k0 + scol, Alds + t*8);
    gload16(A  + (size_t)(m0 + srow + 64)*K + k0 + scol, Alds + 2048 + t*8);
    gload16(Bw + (size_t)(n0 + srow     )*K + k0 + scol, Blds + t*8);
    gload16(Bw + (size_t)(n0 + srow + 64)*K + k0 + scol, Blds + 2048 + t*8);
    asm volatile("s_waitcnt vmcnt(0)" ::: "memory");
    __syncthreads();
    short8 afrag[4], bfrag[4];
    #pragma unroll
    for (int mb = 0; mb < 4; ++mb)
      afrag[mb] = *reinterpret_cast<const short8*>(Alds + (wm + mb*16 + lr)*32 + lg*8);
    #pragma unroll
    for (int nb = 0; nb < 4; ++nb)
      bfrag[nb] = *reinterpret_cast<const short8*>(Blds + (wn + nb*16 + lr)*32 + lg*8);
    #pragma unroll
    for (int mb = 0; mb < 4; ++mb)
      #pragma unroll
      for (int nb = 0; nb < 4; ++nb)
        acc[mb][nb] = __builtin_amdgcn_mfma_f32_16x16x32_bf16(afrag[mb], bfrag[nb], acc[mb][nb], 0, 0, 0);
  }
  #pragma unroll
  for (int mb = 0; mb < 4; ++mb){
    #pragma unroll
    for (int nb = 0; nb < 4; ++nb){
      const int gn = n0 + wn + nb*16 + lr;
      const float biasv = bias[gn];
      #pragma unroll
      for (int r = 0; r < 4; ++r){
        const int gm = m0 + wm + mb*16 + lg*4 + r;
        float v = acc[mb][nb][r] + biasv;
        const int b_ = gm >> 11, s_ = gm & 2047, h_ = gn >> 6, d_ = gn & 63;
        if (!vmode)
          outp[((size_t)(b_*NH + h_)*SS + s_)*HD + d_] = f2bf(v);
        else
          outp[((size_t)(b_*NH + h_)*HD + d_)*SS + s_] = f2bf(v);
      }
    }
  }
}

// ---------- out-projection GEMM: f32 out, * stability ----------
__global__ __launch_bounds__(256) void gemm_out(const unsigned short* __restrict__ A,
                                                const unsigned short* __restrict__ Bw,
                                                const float* __restrict__ bias,
                                                float* __restrict__ outp,
                                                const float* __restrict__ oscale_p){
  __shared__ unsigned short Alds[128*32];
  __shared__ unsigned short Blds[128*32];
  const int K = DM, N = DM;
  const int t = threadIdx.x;
  const int l = t & 63;
  const int w = t >> 6;
  const int m0 = blockIdx.y * 128, n0 = blockIdx.x * 128;
  const int wm = (w & 1)*64, wn = (w >> 1)*64;
  const int srow = t >> 2;
  const int scol = (t & 3)*8;
  const int lr = l & 15, lg = l >> 4;
  float4v acc[4][4] = {};
  for (int k0 = 0; k0 < K; k0 += 32){
    __syncthreads();
    gload16(A  + (size_t)(m0 + srow     )*K + k0 + scol, Alds + t*8);
    gload16(A  + (size_t)(m0 + srow + 64)*K + k0 + scol, Alds + 2048 + t*8);
    gload16(Bw + (size_t)(n0 + srow     )*K + k0 + scol, Blds + t*8);
    gload16(Bw + (size_t)(n0 + srow + 64)*K + k0 + scol, Blds + 2048 + t*8);
    asm volatile("s_waitcnt vmcnt(0)" ::: "memory");
    __syncthreads();
    short8 afrag[4], bfrag[4];
    #pragma unroll
    for (int mb = 0; mb < 4; ++mb)
      afrag[mb] = *reinterpret_cast<const short8*>(Alds + (wm + mb*16 + lr)*32 + lg*8);
    #pragma unroll
    for (int nb = 0; nb < 4; ++nb)
      bfrag[nb] = *reinterpret_cast<const short8*>(Blds + (wn + nb*16 + lr)*32 + lg*8);
    #pragma unroll
    for (int mb = 0; mb < 4; ++mb)
      #pragma unroll
      for (int nb = 0; nb < 4; ++nb)
        acc[mb][nb] = __builtin_amdgcn_mfma_f32_16x16x32_bf16(afrag[mb], bfrag[nb], acc[mb][nb], 0, 0, 0);
  }
  const float osc = oscale_p[0];
  #pragma unroll
  for (int mb = 0; mb < 4; ++mb){
    #pragma unroll
    for (int nb = 0; nb < 4; ++nb){
      const int gn = n0 + wn + nb*16 + lr;
      const float biasv = bias[gn];
      #pragma unroll
      for (int r = 0; r < 4; ++r){
        const int gm = m0 + wm + mb*16 + lg*4 + r;
        outp[(size_t)gm*N + gn] = (acc[mb][nb][r] + biasv) * osc;
      }
    }
  }
}

// ---------- fused attention: QBLK=32, XCD-pinned K/V, swapped-operand QK ----
// Grid: (bh=32, qt=64); blockIdx.x=bh -> all q-tiles of one (b,h) on one XCD
// (K/V L2-resident). attnW path: register shuffle (__shfl, pure SSA - no LDS
// tile, no fences, compiler-safe) gathers each dest lane's 4 contiguous
// floats from the one source lane holding them -> every store instruction
// covers 8 full 128B lines -> NT stores with no write-allocate RMW (r5/r6)
// and no L2 pollution. PV: eA/eB ARE the 16x16x16 A-frags (k=lg*4..+3), so
// PV needs no cross-lane movement at all (K=16 MFMA; bpermute fallback if
// the builtin is unavailable).
__global__ __launch_bounds__(256, 6) void attn_kernel(
    const unsigned short* __restrict__ Qh,   // [B*H][S][64] bf16
    const unsigned short* __restrict__ Kh,   // [B*H][S][64] bf16
    const unsigned short* __restrict__ Vt,   // [B*H][64][S] bf16
    unsigned short* __restrict__ AO,         // [B][S][1024] bf16
    float* __restrict__ attnW,               // [B*H][S][S] f32
    const float* __restrict__ phase,         // [B]
    const float* __restrict__ pc,            // [16]
    const float* __restrict__ ascale)        // [1]
{
  __shared__ float mred[4][32], lred[4][32];
  __shared__ __attribute__((aligned(16))) float ored[4][32*32]; // reused 2x

  const int t = threadIdx.x;
  const int w = t >> 6, l = t & 63;
  const int lr = l & 15, lg = l >> 4;
  const int bh = blockIdx.x, qt = blockIdx.y;
  const int b = bh >> 4, h = bh & 15;
  const int q0 = qt*32;
  const float scale_eff = 0.125f * ascale[0] * (1.0f + pc[h] * sinf(phase[b]));

  const unsigned short* qbase = Qh + ((size_t)bh*SS + q0 + lr)*HD + lg*8;
  short8 aq[2][2];
  aq[0][0] = *reinterpret_cast<const short8*>(qbase);
  aq[0][1] = *reinterpret_cast<const short8*>(qbase + 32);
  aq[1][0] = *reinterpret_cast<const short8*>(qbase + 16*HD);
  aq[1][1] = *reinterpret_cast<const short8*>(qbase + 16*HD + 32);

  const int tbase = w * 512;
  const unsigned short* kbase = Kh + ((size_t)bh*SS + tbase + lr)*HD + lg*8;

  // ---- pass 1: per-lane online (m,l) per q-subtile
  float m[2] = {-1e30f, -1e30f}, lsum[2] = {0.f, 0.f};
  #pragma unroll 2
  for (int tb = 0; tb < 32; ++tb){
    const unsigned short* kp = kbase + (size_t)tb*16*HD;
    short8 bk0 = *reinterpret_cast<const short8*>(kp);
    short8 bk1 = *reinterpret_cast<const short8*>(kp + 32);
    #pragma unroll
    for (int qs = 0; qs < 2; ++qs){
      float4v pacc = {};
      pacc = __builtin_amdgcn_mfma_f32_16x16x32_bf16(bk0, aq[qs][0], pacc, 0, 0, 0);
      pacc = __builtin_amdgcn_mfma_f32_16x16x32_bf16(bk1, aq[qs][1], pacc, 0, 0, 0);
      const float s0 = pacc[0]*scale_eff, s1 = pacc[1]*scale_eff;
      const float s2 = pacc[2]*scale_eff, s3 = pacc[3]*scale_eff;
      const float smax = fmaxf(fmaxf(s0, s1), fmaxf(s2, s3));
      const float nm = fmaxf(m[qs], smax);
      lsum[qs] = lsum[qs]*__expf(m[qs] - nm)
               + __expf(s0 - nm) + __expf(s1 - nm) + __expf(s2 - nm) + __expf(s3 - nm);
      m[qs] = nm;
    }
  }
  #pragma unroll
  for (int mask = 16; mask < 64; mask <<= 1){
    #pragma unroll
    for (int qs = 0; qs < 2; ++qs){
      float om = __shfl_xor(m[qs], mask, 64);
      float ol = __shfl_xor(lsum[qs], mask, 64);
      float nm = fmaxf(m[qs], om);
      lsum[qs] = lsum[qs]*__expf(m[qs] - nm) + ol*__expf(om - nm);
      m[qs] = nm;
    }
  }
  if (l < 16){
    mred[w][lr] = m[0];      lred[w][lr] = lsum[0];
    mred[w][16+lr] = m[1];   lred[w][16+lr] = lsum[1];
  }
  __syncthreads();
  float rm[2], rrl[2];
  #pragma unroll
  for (int qs = 0; qs < 2; ++qs){
    const int row = qs*16 + lr;
    float fm = mred[0][row], fl = lred[0][row];
    #pragma unroll
    for (int ww = 1; ww < 4; ++ww){
      float om = mred[ww][row], ol = lred[ww][row];
      float nm = fmaxf(fm, om);
      fl = fl*__expf(fm - nm) + ol*__expf(om - nm);
      fm = nm;
    }
    rm[qs] = fm; rrl[qs] = 1.0f/fl;
  }

  // ---- pass 2: recompute, normalize, shuffle -> full-line NT stores + PV
  float4v oacc[2][4] = {};
  float* gws0 = attnW + ((size_t)bh*SS + q0)*SS + tbase;   // qs=0 rows
  float* gws1 = gws0 + (size_t)16*SS;                      // qs=1 rows
  const int row0 = l >> 3;              // 0..7: dest row within 8-row group
  const int cgs  = l & 7;               // 0..7: dest 16B col-group
  const int src_base = ((cgs & 3) << 4) + row0;   // source lane (lg=cg&3, lr=row)
#if PV_DIRECT
  const unsigned short* vbase4 = Vt + ((size_t)bh*HD + lr)*SS + tbase + lg*4;
#else
  const unsigned short* vbase8 = Vt + ((size_t)bh*HD + lr)*SS + tbase + lg*8;
  const int idxA = (((lg & 1)*2)*16 + lr)*4;
  const int idxB = idxA + 64;
  const bool hi = (lg >= 2);
#endif

  for (int tp = 0; tp < 16; ++tp){
    const int tloc = tp*32;
    const unsigned short* kpA = kbase + (size_t)tloc*HD;
    short8 k0A = *reinterpret_cast<const short8*>(kpA);
    short8 k1A = *reinterpret_cast<const short8*>(kpA + 32);
    short8 k0B = *reinterpret_cast<const short8*>(kpA + 16*HD);
    short8 k1B = *reinterpret_cast<const short8*>(kpA + 16*HD + 32);
#if !PV_DIRECT
    short8 bv[4];
    #pragma unroll
    for (int dt = 0; dt < 4; ++dt)
      bv[dt] = *reinterpret_cast<const short8*>(vbase8 + (size_t)(dt*16)*SS + tloc);
#endif

    #pragma unroll
    for (int qs = 0; qs < 2; ++qs){
      float4v pA = {};
      pA = __builtin_amdgcn_mfma_f32_16x16x32_bf16(k0A, aq[qs][0], pA, 0, 0, 0);
      pA = __builtin_amdgcn_mfma_f32_16x16x32_bf16(k1A, aq[qs][1], pA, 0, 0, 0);
      float4v pB = {};
      pB = __builtin_amdgcn_mfma_f32_16x16x32_bf16(k0B, aq[qs][0], pB, 0, 0, 0);
      pB = __builtin_amdgcn_mfma_f32_16x16x32_bf16(k1B, aq[qs][1], pB, 0, 0, 0);
      float4v eA, eB;
      eA.x = __expf(pA[0]*scale_eff - rm[qs])*rrl[qs];
      eA.y = __expf(pA[1]*scale_eff - rm[qs])*rrl[qs];
      eA.z = __expf(pA[2]*scale_eff - rm[qs])*rrl[qs];
      eA.w = __expf(pA[3]*scale_eff - rm[qs])*rrl[qs];
      eB.x = __expf(pB[0]*scale_eff - rm[qs])*rrl[qs];
      eB.y = __expf(pB[1]*scale_eff - rm[qs])*rrl[qs];
      eB.z = __expf(pB[2]*scale_eff - rm[qs])*rrl[qs];
      eB.w = __expf(pB[3]*scale_eff - rm[qs])*rrl[qs];

      // ---- PV
#if PV_DIRECT
      // eA/eB are already the 16x16x16 A-frags: A[m=lr][k=lg*4..+3]
      short4v paA, paB;
      paA[0]=(short)f2bf(eA.x); paA[1]=(short)f2bf(eA.y);
      paA[2]=(short)f2bf(eA.z); paA[3]=(short)f2bf(eA.w);
      paB[0]=(short)f2bf(eB.x); paB[1]=(short)f2bf(eB.y);
      paB[2]=(short)f2bf(eB.z); paB[3]=(short)f2bf(eB.w);
      #pragma unroll
      for (int dt = 0; dt < 4; ++dt){
        const short4v vfA = *reinterpret_cast<const short4v*>(vbase4 + (size_t)(dt*16)*SS + tloc);
        const short4v vfB = *reinterpret_cast<const short4v*>(vbase4 + (size_t)(dt*16)*SS + tloc + 16);
        oacc[qs][dt] = __builtin_amdgcn_mfma_f32_16x16x16bf16_1k(paA, vfA, oacc[qs][dt], 0, 0, 0);
        oacc[qs][dt] = __builtin_amdgcn_mfma_f32_16x16x16bf16_1k(paB, vfB, oacc[qs][dt], 0, 0, 0);
      }
#else
      const int w0A = ((int)f2bf(eA.y) << 16) | (int)f2bf(eA.x);
      const int w1A = ((int)f2bf(eA.w) << 16) | (int)f2bf(eA.z);
      const int w0B = ((int)f2bf(eB.y) << 16) | (int)f2bf(eB.x);
      const int w1B = ((int)f2bf(eB.w) << 16) | (int)f2bf(eB.z);
      const int a0 = __builtin_amdgcn_ds_bpermute(idxA, w0A);
      const int b0 = __builtin_amdgcn_ds_bpermute(idxA, w0B);
      const int a1 = __builtin_amdgcn_ds_bpermute(idxA, w1A);
      const int b1 = __builtin_amdgcn_ds_bpermute(idxA, w1B);
      const int a2 = __builtin_amdgcn_ds_bpermute(idxB, w0A);
      const int b2 = __builtin_amdgcn_ds_bpermute(idxB, w0B);
      const int a3 = __builtin_amdgcn_ds_bpermute(idxB, w1A);
      const int b3 = __builtin_amdgcn_ds_bpermute(idxB, w1B);
      int4v words;
      words.x = hi ? b0 : a0;
      words.y = hi ? b1 : a1;
      words.z = hi ? b2 : a2;
      words.w = hi ? b3 : a3;
      const short8 pa = __builtin_bit_cast(short8, words);
      #pragma unroll
      for (int dt = 0; dt < 4; ++dt)
        oacc[qs][dt] = __builtin_amdgcn_mfma_f32_16x16x32_bf16(pa, bv[dt], oacc[qs][dt], 0, 0, 0);
#endif

      // ---- attnW store: shuffle-gather so each instr covers 8 full lines.
      // dest lane (row0+rep*8, cgs) pulls 4 floats from src lane
      // (cgs&3)*16 + row0 + rep*8 (eA if cgs<4 else eB), regs 0..3.
      float* gws = qs ? gws1 : gws0;
      #pragma unroll
      for (int rep = 0; rep < 2; ++rep){
        const int src = src_base + rep*8;
        float4v st;
        {
          const float fa0 = __shfl(eA.x, src, 64), fb0 = __shfl(eB.x, src, 64);
          const float fa1 = __shfl(eA.y, src, 64), fb1 = __shfl(eB.y, src, 64);
          const float fa2 = __shfl(eA.z, src, 64), fb2 = __shfl(eB.z, src, 64);
          const float fa3 = __shfl(eA.w, src, 64), fb3 = __shfl(eB.w, src, 64);
          st.x = (cgs < 4) ? fa0 : fb0;
          st.y = (cgs < 4) ? fa1 : fb1;
          st.z = (cgs < 4) ? fa2 : fb2;
          st.w = (cgs < 4) ? fa3 : fb3;
        }
        __builtin_nontemporal_store(st,
          reinterpret_cast<float4v*>(gws + (size_t)(row0 + rep*8)*SS + tloc + cgs*4));
      }
    }
  }

  // ---- cross-wave O reduce in two 16-col chunks (reuses ored)
  #pragma unroll
  for (int c = 0; c < 2; ++c){
    if (c) __syncthreads();
    #pragma unroll
    for (int qs = 0; qs < 2; ++qs)
      #pragma unroll
      for (int dl = 0; dl < 2; ++dl)
        #pragma unroll
        for (int r = 0; r < 4; ++r)
          ored[w][(qs*16 + lg*4 + r)*32 + dl*16 + lr] = oacc[qs][c*2 + dl][r];
    __syncthreads();
    const int row = t >> 3, c4 = (t & 7);
    const float4v* o0 = reinterpret_cast<const float4v*>(&ored[0][0]);
    const int fi = row*8 + c4;
    float4v s = o0[fi];
    s += o0[fi + 256];
    s += o0[fi + 512];
    s += o0[fi + 768];
    ushort4v o4;
    o4.x = f2bf(s.x); o4.y = f2bf(s.y); o4.z = f2bf(s.z); o4.w = f2bf(s.w);
    *reinterpret_cast<ushort4v*>(AO + ((size_t)b*SS + q0 + row)*DM + h*HD + c*32 + c4*4) = o4;
  }
}

extern "C" void kernel_launch(void* const* d_in, const int* in_sizes, int n_in,
                              void* d_out, int out_size, void* d_ws, size_t ws_size,
                              hipStream_t stream){
  const float* q      = (const float*)d_in[0];
  const float* k      = (const float*)d_in[1];
  const float* v      = (const float*)d_in[2];
  const float* phase  = (const float*)d_in[3];
  const float* Wq     = (const float*)d_in[4];
  const float* bq     = (const float*)d_in[5];
  const float* Wk     = (const float*)d_in[6];
  const float* bk     = (const float*)d_in[7];
  const float* Wv     = (const float*)d_in[8];
  const float* bv     = (const float*)d_in[9];
  const float* Wo     = (const float*)d_in[10];
  const float* bo     = (const float*)d_in[11];
  const float* pc     = (const float*)d_in[12];
  const float* ascale = (const float*)d_in[13];
  const float* stab   = (const float*)d_in[14];

  unsigned short* Xq  = (unsigned short*)d_ws;
  unsigned short* Xk  = Xq  + 4194304;
  unsigned short* Xv  = Xk  + 4194304;
  unsigned short* Wqb = Xv  + 4194304;
  unsigned short* Wkb = Wqb + 1048576;
  unsigned short* Wvb = Wkb + 1048576;
  unsigned short* Wob = Wvb + 1048576;
  unsigned short* Qh  = Wob + 1048576;
  unsigned short* Kh  = Qh  + 4194304;
  unsigned short* Vt  = Kh  + 4194304;
  unsigned short* AO  = Vt  + 4194304;   // total 64 MB of ws

  float* out0  = (float*)d_out;
  float* attnW = out0 + (size_t)MTOT*DM;

  cvt3_kernel<<<dim3(512,1,3), 256, 0, stream>>>(q, k, v, Xq, Xk, Xv, MTOT*DM);
  cvt4_kernel<<<dim3(128,1,4), 256, 0, stream>>>(Wq, Wk, Wv, Wo, Wqb, Wkb, Wvb, Wob, DM*DM);

  gemm_proj<<<dim3(DM/128, MTOT/128, 3), 256, 0, stream>>>(
      Xq, Xk, Xv, Wqb, Wkb, Wvb, bq, bk, bv, Qh, Kh, Vt);

  attn_kernel<<<dim3(32, SS/32, 1), 256, 0, stream>>>(Qh, Kh, Vt, AO, attnW,
                                                      phase, pc, ascale);

  gemm_out<<<dim3(DM/128, MTOT/128, 1), 256, 0, stream>>>(AO, Wob, bo, out0, stab);
}

// Round 9
// 296.059 us; speedup vs baseline: 1.9018x; 1.9018x over previous
//
#include <hip/hip_runtime.h>
#include <hip/hip_bf16.h>
#include <cstdint>
#include <cstddef>
#include <cmath>

#define NH 16
#define HD 64
#define SS 2048
#define DM 1024
#define MTOT 4096   // B*S

typedef __attribute__((ext_vector_type(8))) short short8;
typedef __attribute__((ext_vector_type(4))) float float4v;
typedef __attribute__((ext_vector_type(4))) int int4v;
typedef __attribute__((ext_vector_type(4))) unsigned short ushort4v;

__device__ __forceinline__ unsigned short f2bf(float f){
  unsigned int u = __builtin_bit_cast(unsigned int, f);
  u += 0x7FFFu + ((u >> 16) & 1u);   // RNE; inputs finite
  return (unsigned short)(u >> 16);
}

__device__ __forceinline__ void gload16(const void* g, void* l){
  __builtin_amdgcn_global_load_lds((const __attribute__((address_space(1))) void*)g,
                                   (__attribute__((address_space(3))) void*)l, 16, 0, 0);
}

// ---------- f32 -> bf16 bulk convert, z-batched ----------
__global__ __launch_bounds__(256) void cvt3_kernel(
    const float* __restrict__ s0, const float* __restrict__ s1, const float* __restrict__ s2,
    unsigned short* __restrict__ d0, unsigned short* __restrict__ d1, unsigned short* __restrict__ d2,
    int n){
  const int z = blockIdx.z;
  const float* src = z==0 ? s0 : (z==1 ? s1 : s2);
  unsigned short* dst = z==0 ? d0 : (z==1 ? d1 : d2);
  for (int i = (blockIdx.x*blockDim.x + threadIdx.x)*4; i < n; i += gridDim.x*blockDim.x*4){
    float4v v = *reinterpret_cast<const float4v*>(src + i);
    ushort4v o;
    o.x = f2bf(v.x); o.y = f2bf(v.y); o.z = f2bf(v.z); o.w = f2bf(v.w);
    *reinterpret_cast<ushort4v*>(dst + i) = o;
  }
}

__global__ __launch_bounds__(256) void cvt4_kernel(
    const float* __restrict__ s0, const float* __restrict__ s1,
    const float* __restrict__ s2, const float* __restrict__ s3,
    unsigned short* __restrict__ d0, unsigned short* __restrict__ d1,
    unsigned short* __restrict__ d2, unsigned short* __restrict__ d3,
    int n){
  const int z = blockIdx.z;
  const float* src = z==0 ? s0 : (z==1 ? s1 : (z==2 ? s2 : s3));
  unsigned short* dst = z==0 ? d0 : (z==1 ? d1 : (z==2 ? d2 : d3));
  for (int i = (blockIdx.x*blockDim.x + threadIdx.x)*4; i < n; i += gridDim.x*blockDim.x*4){
    float4v v = *reinterpret_cast<const float4v*>(src + i);
    ushort4v o;
    o.x = f2bf(v.x); o.y = f2bf(v.y); o.z = f2bf(v.z); o.w = f2bf(v.w);
    *reinterpret_cast<ushort4v*>(dst + i) = o;
  }
}

// ---------- batched projection GEMM: z in {q,k,v}; z==2 writes V^T ----------
__global__ __launch_bounds__(256) void gemm_proj(
    const unsigned short* __restrict__ X0, const unsigned short* __restrict__ X1, const unsigned short* __restrict__ X2,
    const unsigned short* __restrict__ W0, const unsigned short* __restrict__ W1, const unsigned short* __restrict__ W2,
    const float* __restrict__ b0, const float* __restrict__ b1, const float* __restrict__ b2,
    unsigned short* __restrict__ O0, unsigned short* __restrict__ O1, unsigned short* __restrict__ O2){
  __shared__ unsigned short Alds[128*32];
  __shared__ unsigned short Blds[128*32];
  const int z = blockIdx.z;
  const unsigned short* A  = z==0 ? X0 : (z==1 ? X1 : X2);
  const unsigned short* Bw = z==0 ? W0 : (z==1 ? W1 : W2);
  const float* bias        = z==0 ? b0 : (z==1 ? b1 : b2);
  unsigned short* outp     = z==0 ? O0 : (z==1 ? O1 : O2);
  const bool vmode = (z == 2);
  const int K = DM;
  const int t = threadIdx.x;
  const int l = t & 63;
  const int w = t >> 6;
  const int m0 = blockIdx.y * 128, n0 = blockIdx.x * 128;
  const int wm = (w & 1)*64, wn = (w >> 1)*64;
  const int srow = t >> 2;
  const int scol = (t & 3)*8;
  const int lr = l & 15, lg = l >> 4;
  float4v acc[4][4] = {};
  for (int k0 = 0; k0 < K; k0 += 32){
    __syncthreads();
    gload16(A  + (size_t)(m0 + srow     )*K + k0 + scol, Alds + t*8);
    gload16(A  + (size_t)(m0 + srow + 64)*K + k0 + scol, Alds + 2048 + t*8);
    gload16(Bw + (size_t)(n0 + srow     )*K + k0 + scol, Blds + t*8);
    gload16(Bw + (size_t)(n0 + srow + 64)*K + k0 + scol, Blds + 2048 + t*8);
    asm volatile("s_waitcnt vmcnt(0)" ::: "memory");
    __syncthreads();
    short8 afrag[4], bfrag[4];
    #pragma unroll
    for (int mb = 0; mb < 4; ++mb)
      afrag[mb] = *reinterpret_cast<const short8*>(Alds + (wm + mb*16 + lr)*32 + lg*8);
    #pragma unroll
    for (int nb = 0; nb < 4; ++nb)
      bfrag[nb] = *reinterpret_cast<const short8*>(Blds + (wn + nb*16 + lr)*32 + lg*8);
    #pragma unroll
    for (int mb = 0; mb < 4; ++mb)
      #pragma unroll
      for (int nb = 0; nb < 4; ++nb)
        acc[mb][nb] = __builtin_amdgcn_mfma_f32_16x16x32_bf16(afrag[mb], bfrag[nb], acc[mb][nb], 0, 0, 0);
  }
  #pragma unroll
  for (int mb = 0; mb < 4; ++mb){
    #pragma unroll
    for (int nb = 0; nb < 4; ++nb){
      const int gn = n0 + wn + nb*16 + lr;
      const float biasv = bias[gn];
      #pragma unroll
      for (int r = 0; r < 4; ++r){
        const int gm = m0 + wm + mb*16 + lg*4 + r;
        float v = acc[mb][nb][r] + biasv;
        const int b_ = gm >> 11, s_ = gm & 2047, h_ = gn >> 6, d_ = gn & 63;
        if (!vmode)
          outp[((size_t)(b_*NH + h_)*SS + s_)*HD + d_] = f2bf(v);
        else
          outp[((size_t)(b_*NH + h_)*HD + d_)*SS + s_] = f2bf(v);
      }
    }
  }
}

// ---------- out-projection GEMM: f32 out, * stability ----------
__global__ __launch_bounds__(256) void gemm_out(const unsigned short* __restrict__ A,
                                                const unsigned short* __restrict__ Bw,
                                                const float* __restrict__ bias,
                                                float* __restrict__ outp,
                                                const float* __restrict__ oscale_p){
  __shared__ unsigned short Alds[128*32];
  __shared__ unsigned short Blds[128*32];
  const int K = DM, N = DM;
  const int t = threadIdx.x;
  const int l = t & 63;
  const int w = t >> 6;
  const int m0 = blockIdx.y * 128, n0 = blockIdx.x * 128;
  const int wm = (w & 1)*64, wn = (w >> 1)*64;
  const int srow = t >> 2;
  const int scol = (t & 3)*8;
  const int lr = l & 15, lg = l >> 4;
  float4v acc[4][4] = {};
  for (int k0 = 0; k0 < K; k0 += 32){
    __syncthreads();
    gload16(A  + (size_t)(m0 + srow     )*K + k0 + scol, Alds + t*8);
    gload16(A  + (size_t)(m0 + srow + 64)*K + k0 + scol, Alds + 2048 + t*8);
    gload16(Bw + (size_t)(n0 + srow     )*K + k0 + scol, Blds + t*8);
    gload16(Bw + (size_t)(n0 + srow + 64)*K + k0 + scol, Blds + 2048 + t*8);
    asm volatile("s_waitcnt vmcnt(0)" ::: "memory");
    __syncthreads();
    short8 afrag[4], bfrag[4];
    #pragma unroll
    for (int mb = 0; mb < 4; ++mb)
      afrag[mb] = *reinterpret_cast<const short8*>(Alds + (wm + mb*16 + lr)*32 + lg*8);
    #pragma unroll
    for (int nb = 0; nb < 4; ++nb)
      bfrag[nb] = *reinterpret_cast<const short8*>(Blds + (wn + nb*16 + lr)*32 + lg*8);
    #pragma unroll
    for (int mb = 0; mb < 4; ++mb)
      #pragma unroll
      for (int nb = 0; nb < 4; ++nb)
        acc[mb][nb] = __builtin_amdgcn_mfma_f32_16x16x32_bf16(afrag[mb], bfrag[nb], acc[mb][nb], 0, 0, 0);
  }
  const float osc = oscale_p[0];
  #pragma unroll
  for (int mb = 0; mb < 4; ++mb){
    #pragma unroll
    for (int nb = 0; nb < 4; ++nb){
      const int gn = n0 + wn + nb*16 + lr;
      const float biasv = bias[gn];
      #pragma unroll
      for (int r = 0; r < 4; ++r){
        const int gm = m0 + wm + mb*16 + lg*4 + r;
        outp[(size_t)gm*N + gn] = (acc[mb][nb][r] + biasv) * osc;
      }
    }
  }
}

// ---------- fused attention: r4 structure + 256B-burst deferred NT stores ---
// Grid: (bh=32, qt=64); blockIdx.x=bh -> all q-tiles of one (b,h) on one XCD
// (K/V L2-resident). Stores: e-vectors for two consecutive 32-col iterations
// are DEFERRED and issued as 4 back-to-back NT instructions per row covering
// 256B contiguous -> matches the HBM/MALL write atom (r8 evidence: 128B
// bursts still RMW: FETCH +537MB, WRITE 2x). occ stays 4 (r5/r8: occ 6
// halves achieved NT write BW).
__global__ __launch_bounds__(256, 4) void attn_kernel(
    const unsigned short* __restrict__ Qh,   // [B*H][S][64] bf16
    const unsigned short* __restrict__ Kh,   // [B*H][S][64] bf16
    const unsigned short* __restrict__ Vt,   // [B*H][64][S] bf16
    unsigned short* __restrict__ AO,         // [B][S][1024] bf16
    float* __restrict__ attnW,               // [B*H][S][S] f32
    const float* __restrict__ phase,         // [B]
    const float* __restrict__ pc,            // [16]
    const float* __restrict__ ascale)        // [1]
{
  __shared__ float mred[4][32], lred[4][32];
  __shared__ __attribute__((aligned(16))) float ored[4][32*32]; // reused 2x

  const int t = threadIdx.x;
  const int w = t >> 6, l = t & 63;
  const int lr = l & 15, lg = l >> 4;
  const int bh = blockIdx.x, qt = blockIdx.y;
  const int b = bh >> 4, h = bh & 15;
  const int q0 = qt*32;
  const float scale_eff = 0.125f * ascale[0] * (1.0f + pc[h] * sinf(phase[b]));

  const unsigned short* qbase = Qh + ((size_t)bh*SS + q0 + lr)*HD + lg*8;
  short8 aq[2][2];
  aq[0][0] = *reinterpret_cast<const short8*>(qbase);
  aq[0][1] = *reinterpret_cast<const short8*>(qbase + 32);
  aq[1][0] = *reinterpret_cast<const short8*>(qbase + 16*HD);
  aq[1][1] = *reinterpret_cast<const short8*>(qbase + 16*HD + 32);

  const int tbase = w * 512;
  const unsigned short* kbase = Kh + ((size_t)bh*SS + tbase + lr)*HD + lg*8;

  // ---- pass 1: per-lane online (m,l) per q-subtile
  float m[2] = {-1e30f, -1e30f}, lsum[2] = {0.f, 0.f};
  #pragma unroll 2
  for (int tb = 0; tb < 32; ++tb){
    const unsigned short* kp = kbase + (size_t)tb*16*HD;
    short8 bk0 = *reinterpret_cast<const short8*>(kp);
    short8 bk1 = *reinterpret_cast<const short8*>(kp + 32);
    #pragma unroll
    for (int qs = 0; qs < 2; ++qs){
      float4v pacc = {};
      pacc = __builtin_amdgcn_mfma_f32_16x16x32_bf16(bk0, aq[qs][0], pacc, 0, 0, 0);
      pacc = __builtin_amdgcn_mfma_f32_16x16x32_bf16(bk1, aq[qs][1], pacc, 0, 0, 0);
      const float s0 = pacc[0]*scale_eff, s1 = pacc[1]*scale_eff;
      const float s2 = pacc[2]*scale_eff, s3 = pacc[3]*scale_eff;
      const float smax = fmaxf(fmaxf(s0, s1), fmaxf(s2, s3));
      const float nm = fmaxf(m[qs], smax);
      lsum[qs] = lsum[qs]*__expf(m[qs] - nm)
               + __expf(s0 - nm) + __expf(s1 - nm) + __expf(s2 - nm) + __expf(s3 - nm);
      m[qs] = nm;
    }
  }
  #pragma unroll
  for (int mask = 16; mask < 64; mask <<= 1){
    #pragma unroll
    for (int qs = 0; qs < 2; ++qs){
      float om = __shfl_xor(m[qs], mask, 64);
      float ol = __shfl_xor(lsum[qs], mask, 64);
      float nm = fmaxf(m[qs], om);
      lsum[qs] = lsum[qs]*__expf(m[qs] - nm) + ol*__expf(om - nm);
      m[qs] = nm;
    }
  }
  if (l < 16){
    mred[w][lr] = m[0];      lred[w][lr] = lsum[0];
    mred[w][16+lr] = m[1];   lred[w][16+lr] = lsum[1];
  }
  __syncthreads();
  float rm[2], rrl[2];
  #pragma unroll
  for (int qs = 0; qs < 2; ++qs){
    const int row = qs*16 + lr;
    float fm = mred[0][row], fl = lred[0][row];
    #pragma unroll
    for (int ww = 1; ww < 4; ++ww){
      float om = mred[ww][row], ol = lred[ww][row];
      float nm = fmaxf(fm, om);
      fl = fl*__expf(fm - nm) + ol*__expf(om - nm);
      fm = nm;
    }
    rm[qs] = fm; rrl[qs] = 1.0f/fl;
  }

  // ---- pass 2: recompute, normalize, PV; stores deferred to 256B bursts
  float4v oacc[2][4] = {};
  float* gwq0 = attnW + ((size_t)bh*SS + q0 + lr)*SS + tbase;
  float* gwq1 = gwq0 + (size_t)16*SS;
  const unsigned short* vbase = Vt + ((size_t)bh*HD + lr)*SS + tbase + lg*8;
  const int idxA = (((lg & 1)*2)*16 + lr)*4;
  const int idxB = idxA + 64;
  const bool hi = (lg >= 2);

  for (int tp2 = 0; tp2 < 8; ++tp2){
    float4v sA[2][2], sB[2][2];   // [half][qs] — all indices compile-time
    #pragma unroll
    for (int half = 0; half < 2; ++half){
      const int tloc = (tp2*2 + half)*32;
      const unsigned short* kpA = kbase + (size_t)tloc*HD;
      short8 k0A = *reinterpret_cast<const short8*>(kpA);
      short8 k1A = *reinterpret_cast<const short8*>(kpA + 32);
      short8 k0B = *reinterpret_cast<const short8*>(kpA + 16*HD);
      short8 k1B = *reinterpret_cast<const short8*>(kpA + 16*HD + 32);
      short8 bv[4];
      #pragma unroll
      for (int dt = 0; dt < 4; ++dt)
        bv[dt] = *reinterpret_cast<const short8*>(vbase + (size_t)(dt*16)*SS + tloc);

      #pragma unroll
      for (int qs = 0; qs < 2; ++qs){
        float4v pA = {};
        pA = __builtin_amdgcn_mfma_f32_16x16x32_bf16(k0A, aq[qs][0], pA, 0, 0, 0);
        pA = __builtin_amdgcn_mfma_f32_16x16x32_bf16(k1A, aq[qs][1], pA, 0, 0, 0);
        float4v pB = {};
        pB = __builtin_amdgcn_mfma_f32_16x16x32_bf16(k0B, aq[qs][0], pB, 0, 0, 0);
        pB = __builtin_amdgcn_mfma_f32_16x16x32_bf16(k1B, aq[qs][1], pB, 0, 0, 0);
        float4v eA, eB;
        eA.x = __expf(pA[0]*scale_eff - rm[qs])*rrl[qs];
        eA.y = __expf(pA[1]*scale_eff - rm[qs])*rrl[qs];
        eA.z = __expf(pA[2]*scale_eff - rm[qs])*rrl[qs];
        eA.w = __expf(pA[3]*scale_eff - rm[qs])*rrl[qs];
        eB.x = __expf(pB[0]*scale_eff - rm[qs])*rrl[qs];
        eB.y = __expf(pB[1]*scale_eff - rm[qs])*rrl[qs];
        eB.z = __expf(pB[2]*scale_eff - rm[qs])*rrl[qs];
        eB.w = __expf(pB[3]*scale_eff - rm[qs])*rrl[qs];
        const int w0A = ((int)f2bf(eA.y) << 16) | (int)f2bf(eA.x);
        const int w1A = ((int)f2bf(eA.w) << 16) | (int)f2bf(eA.z);
        const int w0B = ((int)f2bf(eB.y) << 16) | (int)f2bf(eB.x);
        const int w1B = ((int)f2bf(eB.w) << 16) | (int)f2bf(eB.z);

        const int a0 = __builtin_amdgcn_ds_bpermute(idxA, w0A);
        const int b0 = __builtin_amdgcn_ds_bpermute(idxA, w0B);
        const int a1 = __builtin_amdgcn_ds_bpermute(idxA, w1A);
        const int b1 = __builtin_amdgcn_ds_bpermute(idxA, w1B);
        const int a2 = __builtin_amdgcn_ds_bpermute(idxB, w0A);
        const int b2 = __builtin_amdgcn_ds_bpermute(idxB, w0B);
        const int a3 = __builtin_amdgcn_ds_bpermute(idxB, w1A);
        const int b3 = __builtin_amdgcn_ds_bpermute(idxB, w1B);
        int4v words;
        words.x = hi ? b0 : a0;
        words.y = hi ? b1 : a1;
        words.z = hi ? b2 : a2;
        words.w = hi ? b3 : a3;
        const short8 pa = __builtin_bit_cast(short8, words);

        #pragma unroll
        for (int dt = 0; dt < 4; ++dt)
          oacc[qs][dt] = __builtin_amdgcn_mfma_f32_16x16x32_bf16(pa, bv[dt], oacc[qs][dt], 0, 0, 0);

        sA[half][qs] = eA;
        sB[half][qs] = eB;
      }
    }
    // deferred stores: per qs, 4 back-to-back NT instrs cover cols
    // [t0, t0+64) per row = 256B contiguous (ascending addresses)
    const int t0 = tp2*64;
    #pragma unroll
    for (int qs = 0; qs < 2; ++qs){
      float* gw = qs ? gwq1 : gwq0;
      __builtin_nontemporal_store(sA[0][qs], reinterpret_cast<float4v*>(gw + t0 + lg*4));
      __builtin_nontemporal_store(sB[0][qs], reinterpret_cast<float4v*>(gw + t0 + 16 + lg*4));
      __builtin_nontemporal_store(sA[1][qs], reinterpret_cast<float4v*>(gw + t0 + 32 + lg*4));
      __builtin_nontemporal_store(sB[1][qs], reinterpret_cast<float4v*>(gw + t0 + 48 + lg*4));
    }
  }

  // ---- cross-wave O reduce in two 16-col chunks (reuses ored)
  #pragma unroll
  for (int c = 0; c < 2; ++c){
    if (c) __syncthreads();
    #pragma unroll
    for (int qs = 0; qs < 2; ++qs)
      #pragma unroll
      for (int dl = 0; dl < 2; ++dl)
        #pragma unroll
        for (int r = 0; r < 4; ++r)
          ored[w][(qs*16 + lg*4 + r)*32 + dl*16 + lr] = oacc[qs][c*2 + dl][r];
    __syncthreads();
    const int row = t >> 3, c4 = (t & 7);
    const float4v* o0 = reinterpret_cast<const float4v*>(&ored[0][0]);
    const int fi = row*8 + c4;
    float4v s = o0[fi];
    s += o0[fi + 256];
    s += o0[fi + 512];
    s += o0[fi + 768];
    ushort4v o4;
    o4.x = f2bf(s.x); o4.y = f2bf(s.y); o4.z = f2bf(s.z); o4.w = f2bf(s.w);
    *reinterpret_cast<ushort4v*>(AO + ((size_t)b*SS + q0 + row)*DM + h*HD + c*32 + c4*4) = o4;
  }
}

extern "C" void kernel_launch(void* const* d_in, const int* in_sizes, int n_in,
                              void* d_out, int out_size, void* d_ws, size_t ws_size,
                              hipStream_t stream){
  const float* q      = (const float*)d_in[0];
  const float* k      = (const float*)d_in[1];
  const float* v      = (const float*)d_in[2];
  const float* phase  = (const float*)d_in[3];
  const float* Wq     = (const float*)d_in[4];
  const float* bq     = (const float*)d_in[5];
  const float* Wk     = (const float*)d_in[6];
  const float* bk     = (const float*)d_in[7];
  const float* Wv     = (const float*)d_in[8];
  const float* bv     = (const float*)d_in[9];
  const float* Wo     = (const float*)d_in[10];
  const float* bo     = (const float*)d_in[11];
  const float* pc     = (const float*)d_in[12];
  const float* ascale = (const float*)d_in[13];
  const float* stab   = (const float*)d_in[14];

  unsigned short* Xq  = (unsigned short*)d_ws;
  unsigned short* Xk  = Xq  + 4194304;
  unsigned short* Xv  = Xk  + 4194304;
  unsigned short* Wqb = Xv  + 4194304;
  unsigned short* Wkb = Wqb + 1048576;
  unsigned short* Wvb = Wkb + 1048576;
  unsigned short* Wob = Wvb + 1048576;
  unsigned short* Qh  = Wob + 1048576;
  unsigned short* Kh  = Qh  + 4194304;
  unsigned short* Vt  = Kh  + 4194304;
  unsigned short* AO  = Vt  + 4194304;   // total 64 MB of ws

  float* out0  = (float*)d_out;
  float* attnW = out0 + (size_t)MTOT*DM;

  cvt3_kernel<<<dim3(512,1,3), 256, 0, stream>>>(q, k, v, Xq, Xk, Xv, MTOT*DM);
  cvt4_kernel<<<dim3(128,1,4), 256, 0, stream>>>(Wq, Wk, Wv, Wo, Wqb, Wkb, Wvb, Wob, DM*DM);

  gemm_proj<<<dim3(DM/128, MTOT/128, 3), 256, 0, stream>>>(
      Xq, Xk, Xv, Wqb, Wkb, Wvb, bq, bk, bv, Qh, Kh, Vt);

  attn_kernel<<<dim3(32, SS/32, 1), 256, 0, stream>>>(Qh, Kh, Vt, AO, attnW,
                                                      phase, pc, ascale);

  gemm_out<<<dim3(DM/128, MTOT/128, 1), 256, 0, stream>>>(AO, Wob, bo, out0, stab);
}